// Round 1
// baseline (1892.168 us; speedup 1.0000x reference)
//
#include <hip/hip_runtime.h>
#include <hip/hip_bf16.h>
#include <cstdint>

#define N_TOK 4096
#define DIM_  1024
#define HID_  4096
#define NEXP  8

typedef __attribute__((ext_vector_type(8))) short short8;
typedef __attribute__((ext_vector_type(4))) float f32x4;

__device__ __forceinline__ unsigned short f32_to_bf16(float f) {
    union { float f; uint32_t u; } v;
    v.f = f;
    uint32_t r = (v.u + 0x7fffu + ((v.u >> 16) & 1u)) >> 16;
    return (unsigned short)r;
}

__device__ __forceinline__ float gelu_exact(float x) {
    return 0.5f * x * (1.0f + erff(x * 0.70710678118654752440f));
}

__device__ __forceinline__ void gl_lds16(const unsigned short* g, unsigned short* l) {
    __builtin_amdgcn_global_load_lds(
        (const __attribute__((address_space(1))) void*)g,
        (__attribute__((address_space(3))) void*)l, 16, 0, 0);
}

// ---------------- Gate: logits -> softmax -> mask/renorm/fallback weights ----
__global__ __launch_bounds__(256)
void gate_kernel(const float* __restrict__ x, const float* __restrict__ wg,
                 const float* __restrict__ bg, float* __restrict__ gates,
                 float* __restrict__ wts)
{
    const int n = blockIdx.x;
    const int t = threadIdx.x;
    float acc[NEXP];
#pragma unroll
    for (int e = 0; e < NEXP; e++) acc[e] = 0.0f;
    const float* xr = x + (size_t)n * DIM_;
    for (int k = t; k < DIM_; k += 256) {
        const float xv = xr[k];
        const float* wr = wg + (size_t)k * NEXP;
#pragma unroll
        for (int e = 0; e < NEXP; e++) acc[e] = fmaf(xv, wr[e], acc[e]);
    }
#pragma unroll
    for (int e = 0; e < NEXP; e++) {
#pragma unroll
        for (int off = 32; off > 0; off >>= 1)
            acc[e] += __shfl_down(acc[e], off, 64);
    }
    __shared__ float red[4][NEXP];
    const int lane = t & 63, wave = t >> 6;
    if (lane == 0) {
#pragma unroll
        for (int e = 0; e < NEXP; e++) red[wave][e] = acc[e];
    }
    __syncthreads();
    if (t == 0) {
        float z[NEXP];
#pragma unroll
        for (int e = 0; e < NEXP; e++)
            z[e] = red[0][e] + red[1][e] + red[2][e] + red[3][e] + bg[e];
        float m = z[0];
#pragma unroll
        for (int e = 1; e < NEXP; e++) m = fmaxf(m, z[e]);
        float p[NEXP], s = 0.0f;
#pragma unroll
        for (int e = 0; e < NEXP; e++) { p[e] = __expf(z[e] - m); s += p[e]; }
        const float invs = 1.0f / s;
        float g[NEXP];
        int top = 0;
#pragma unroll
        for (int e = 0; e < NEXP; e++) {
            g[e] = p[e] * invs;
            gates[(size_t)n * NEXP + e] = g[e];
            if (g[e] > g[top]) top = e;
        }
        float w[NEXP], sm = 0.0f;
        int cnt = 0;
#pragma unroll
        for (int e = 0; e < NEXP; e++) {
            const bool mk = (g[e] >= 0.3f);
            const float ms = mk ? g[e] : 0.0f;
            sm += ms; cnt += mk ? 1 : 0;
            w[e] = ms;
        }
        if (cnt == 0) {
#pragma unroll
            for (int e = 0; e < NEXP; e++) w[e] = 0.0f;
            w[top] = 1.0f;
        } else {
            const float inv = 1.0f / (sm + 1e-6f);
#pragma unroll
            for (int e = 0; e < NEXP; e++) w[e] *= inv;
        }
#pragma unroll
        for (int e = 0; e < NEXP; e++) wts[(size_t)n * NEXP + e] = w[e];
    }
}

// ---------------- fp32 -> bf16 elementwise (layout preserved) ----------------
__global__ __launch_bounds__(256)
void cvt_bf16_kernel(const float* __restrict__ in, unsigned short* __restrict__ out,
                     long n4)
{
    const long i = (long)blockIdx.x * 256 + threadIdx.x;
    if (i < n4) {
        const float4 v = ((const float4*)in)[i];
        ushort4 o;
        o.x = f32_to_bf16(v.x);
        o.y = f32_to_bf16(v.y);
        o.z = f32_to_bf16(v.z);
        o.w = f32_to_bf16(v.w);
        ((ushort4*)out)[i] = o;
    }
}

// ---------------- fp32 [E][R][C] -> bf16 [E][C][R] (transpose + convert) -----
__global__ __launch_bounds__(256)
void transpose_cvt(const float* __restrict__ in, unsigned short* __restrict__ out,
                   int R, int C)
{
    __shared__ float tile[32][33];
    const int e  = blockIdx.z;
    const int c0 = blockIdx.x * 32;
    const int r0 = blockIdx.y * 32;
    const int tx = threadIdx.x;  // 0..31
    const int ty = threadIdx.y;  // 0..7
    const float* src = in + (size_t)e * R * C;
    unsigned short* dst = out + (size_t)e * R * C;
#pragma unroll
    for (int i = 0; i < 4; i++)
        tile[ty + i * 8][tx] = src[(size_t)(r0 + ty + i * 8) * C + (c0 + tx)];
    __syncthreads();
#pragma unroll
    for (int i = 0; i < 4; i++)
        dst[(size_t)(c0 + ty + i * 8) * R + (r0 + tx)] = f32_to_bf16(tile[tx][ty + i * 8]);
}

// ---------------- bf16 GEMM, B supplied transposed ([Nc][K]), fp32 accum -----
// MODE 0: C_bf16[row*Nc+col] = bf16(gelu(acc + bias[col]))
// MODE 1: Cf[row*Nc+col] (+)= wts[row*8+eidx] * (acc + bias[col])
template <int MODE>
__global__ __launch_bounds__(256)
void gemm_bt(const unsigned short* __restrict__ A, const unsigned short* __restrict__ Bt,
             int K, int Nc,
             const float* __restrict__ bias,
             unsigned short* __restrict__ Cbf,
             float* __restrict__ Cf,
             const float* __restrict__ wts, int eidx, int accum)
{
    __shared__ __align__(16) unsigned short sA[128 * 32];
    __shared__ __align__(16) unsigned short sB[128 * 32];
    const int tid  = threadIdx.x;
    const int lane = tid & 63;
    const int wave = tid >> 6;
    const int wr = wave >> 1, wc = wave & 1;
    const int rowBase = blockIdx.y * 128;
    const int colBase = blockIdx.x * 128;

    f32x4 acc[4][4];
#pragma unroll
    for (int i = 0; i < 4; i++)
#pragma unroll
        for (int j = 0; j < 4; j++)
#pragma unroll
            for (int r = 0; r < 4; r++) acc[i][j][r] = 0.0f;

    // staging: thread t stages 16B chunks; LDS dest = wave-uniform base + lane*16
    const int sr = tid >> 2;            // row within 64-row half
    const int sc = (tid & 3) << 3;      // k-offset (8 bf16 = 16B)
    const unsigned short* ga0 = A  + (size_t)(rowBase + sr) * K + sc;
    const unsigned short* ga1 = ga0 + (size_t)64 * K;
    const unsigned short* gb0 = Bt + (size_t)(colBase + sr) * K + sc;
    const unsigned short* gb1 = gb0 + (size_t)64 * K;
    unsigned short* la0 = sA + tid * 8;
    unsigned short* la1 = sA + 2048 + tid * 8;
    unsigned short* lb0 = sB + tid * 8;
    unsigned short* lb1 = sB + 2048 + tid * 8;

    const int aoff = (wr * 64 + (lane & 15)) * 32 + ((lane >> 4) << 3);
    const int boff = (wc * 64 + (lane & 15)) * 32 + ((lane >> 4) << 3);

    for (int k0 = 0; k0 < K; k0 += 32) {
        gl_lds16(ga0 + k0, la0);
        gl_lds16(ga1 + k0, la1);
        gl_lds16(gb0 + k0, lb0);
        gl_lds16(gb1 + k0, lb1);
        __syncthreads();
        short8 av[4], bv[4];
#pragma unroll
        for (int i = 0; i < 4; i++) av[i] = *(const short8*)(sA + aoff + i * 16 * 32);
#pragma unroll
        for (int j = 0; j < 4; j++) bv[j] = *(const short8*)(sB + boff + j * 16 * 32);
#pragma unroll
        for (int i = 0; i < 4; i++)
#pragma unroll
            for (int j = 0; j < 4; j++)
                acc[i][j] = __builtin_amdgcn_mfma_f32_16x16x32_bf16(av[i], bv[j], acc[i][j], 0, 0, 0);
        __syncthreads();
    }

    // epilogue: C/D layout col=lane&15, row=(lane>>4)*4+r  [measured m89/m91]
    const int crow = rowBase + wr * 64 + ((lane >> 4) << 2);
    const int ccol = colBase + wc * 64 + (lane & 15);
#pragma unroll
    for (int i = 0; i < 4; i++) {
#pragma unroll
        for (int j = 0; j < 4; j++) {
            const int col = ccol + j * 16;
            const float b = bias[col];
#pragma unroll
            for (int r = 0; r < 4; r++) {
                const int row = crow + i * 16 + r;
                const float v = acc[i][j][r] + b;
                if (MODE == 0) {
                    Cbf[(size_t)row * Nc + col] = f32_to_bf16(gelu_exact(v));
                } else {
                    const float w = wts[(size_t)row * NEXP + eidx];
                    const size_t idx = (size_t)row * Nc + col;
                    const float prev = accum ? Cf[idx] : 0.0f;
                    Cf[idx] = prev + w * v;
                }
            }
        }
    }
}

extern "C" void kernel_launch(void* const* d_in, const int* in_sizes, int n_in,
                              void* d_out, int out_size, void* d_ws, size_t ws_size,
                              hipStream_t stream)
{
    const float* x  = (const float*)d_in[0];
    const float* ei = (const float*)d_in[1];
    const float* wg = (const float*)d_in[2];
    const float* bg = (const float*)d_in[3];
    const float* w1 = (const float*)d_in[4];
    const float* b1 = (const float*)d_in[5];
    const float* w2 = (const float*)d_in[6];
    const float* b2 = (const float*)d_in[7];

    float* fused = (float*)d_out;                       // [N, DIM]
    float* gates = fused + (size_t)N_TOK * DIM_;        // [N, E]

    // workspace layout (~224.1 MB)
    unsigned short* xb  = (unsigned short*)d_ws;                    // [E][N][DIM] bf16
    unsigned short* w1t = xb  + (size_t)NEXP * N_TOK * DIM_;        // [E][HID][DIM] bf16
    unsigned short* w2t = w1t + (size_t)NEXP * HID_ * DIM_;         // [E][DIM][HID] bf16
    unsigned short* hbf = w2t + (size_t)NEXP * DIM_ * HID_;         // [N][HID] bf16
    float* wts = (float*)(hbf + (size_t)N_TOK * HID_);              // [N][E] fp32

    // 1) gate scores + combine weights (fp32, fallback folded into weights)
    gate_kernel<<<N_TOK, 256, 0, stream>>>(x, wg, bg, gates, wts);

    // 2) operand prep: bf16 cast (K-contiguous) + weight transposes
    {
        const long n4 = (long)NEXP * N_TOK * DIM_ / 4;
        cvt_bf16_kernel<<<(unsigned)((n4 + 255) / 256), 256, 0, stream>>>(ei, xb, n4);
    }
    transpose_cvt<<<dim3(HID_ / 32, DIM_ / 32, NEXP), dim3(32, 8), 0, stream>>>(w1, w1t, DIM_, HID_);
    transpose_cvt<<<dim3(DIM_ / 32, HID_ / 32, NEXP), dim3(32, 8), 0, stream>>>(w2, w2t, HID_, DIM_);

    // 3) per-expert FFN: h = gelu(Xe @ W1e + b1e); fused (+)= w .* (h @ W2e + b2e)
    for (int e = 0; e < NEXP; e++) {
        gemm_bt<0><<<dim3(HID_ / 128, N_TOK / 128), 256, 0, stream>>>(
            xb + (size_t)e * N_TOK * DIM_,
            w1t + (size_t)e * HID_ * DIM_,
            DIM_, HID_,
            b1 + (size_t)e * HID_,
            hbf, nullptr, nullptr, 0, 0);
        gemm_bt<1><<<dim3(DIM_ / 128, N_TOK / 128), 256, 0, stream>>>(
            hbf,
            w2t + (size_t)e * DIM_ * HID_,
            HID_, DIM_,
            b2 + (size_t)e * DIM_,
            nullptr, fused, wts, e, e > 0);
    }
}

// Round 2
// 716.098 us; speedup vs baseline: 2.6423x; 2.6423x over previous
//
#include <hip/hip_runtime.h>
#include <hip/hip_bf16.h>
#include <cstdint>

#define N_TOK 4096
#define DIM_  1024
#define HID_  4096
#define NEXP  8
#define HHALF 2048           // HID is processed in two halves to shrink h buffer
#define CAP   (3 * N_TOK)    // sum of per-expert gathered rows is provably <= 3N

typedef __attribute__((ext_vector_type(8))) short short8;
typedef __attribute__((ext_vector_type(4))) float f32x4;

__device__ __forceinline__ unsigned short f32_to_bf16(float f) {
    union { float f; uint32_t u; } v;
    v.f = f;
    uint32_t r = (v.u + 0x7fffu + ((v.u >> 16) & 1u)) >> 16;
    return (unsigned short)r;
}

__device__ __forceinline__ float gelu_exact(float x) {
    return 0.5f * x * (1.0f + erff(x * 0.70710678118654752440f));
}

__device__ __forceinline__ void gl_lds16(const unsigned short* g, unsigned short* l) {
    __builtin_amdgcn_global_load_lds(
        (const __attribute__((address_space(1))) void*)g,
        (__attribute__((address_space(3))) void*)l, 16, 0, 0);
}

// ---------------- zero-init fused output + per-expert counters ---------------
__global__ __launch_bounds__(256)
void zero_init_kernel(float* __restrict__ fused, int* __restrict__ cnt)
{
    const int b = blockIdx.x;
    if (b < N_TOK) {
        float4* p = (float4*)(fused + (size_t)b * DIM_);
        const int t = threadIdx.x;
        p[t] = make_float4(0.f, 0.f, 0.f, 0.f);  // 256 threads x 4 floats = 1024
    } else if (threadIdx.x < NEXP) {
        cnt[threadIdx.x] = 0;
    }
}

// ---------------- Gate: logits -> softmax -> mask/renorm/fallback weights ----
// Math kept bit-identical to round 1 (passed) — threshold compares are fragile.
__global__ __launch_bounds__(256)
void gate_kernel(const float* __restrict__ x, const float* __restrict__ wg,
                 const float* __restrict__ bg, float* __restrict__ gates,
                 float* __restrict__ wts, int* __restrict__ cnt)
{
    const int n = blockIdx.x;
    const int t = threadIdx.x;
    float acc[NEXP];
#pragma unroll
    for (int e = 0; e < NEXP; e++) acc[e] = 0.0f;
    const float* xr = x + (size_t)n * DIM_;
    for (int k = t; k < DIM_; k += 256) {
        const float xv = xr[k];
        const float* wr = wg + (size_t)k * NEXP;
#pragma unroll
        for (int e = 0; e < NEXP; e++) acc[e] = fmaf(xv, wr[e], acc[e]);
    }
#pragma unroll
    for (int e = 0; e < NEXP; e++) {
#pragma unroll
        for (int off = 32; off > 0; off >>= 1)
            acc[e] += __shfl_down(acc[e], off, 64);
    }
    __shared__ float red[4][NEXP];
    const int lane = t & 63, wave = t >> 6;
    if (lane == 0) {
#pragma unroll
        for (int e = 0; e < NEXP; e++) red[wave][e] = acc[e];
    }
    __syncthreads();
    if (t == 0) {
        float z[NEXP];
#pragma unroll
        for (int e = 0; e < NEXP; e++)
            z[e] = red[0][e] + red[1][e] + red[2][e] + red[3][e] + bg[e];
        float m = z[0];
#pragma unroll
        for (int e = 1; e < NEXP; e++) m = fmaxf(m, z[e]);
        float p[NEXP], s = 0.0f;
#pragma unroll
        for (int e = 0; e < NEXP; e++) { p[e] = __expf(z[e] - m); s += p[e]; }
        const float invs = 1.0f / s;
        float g[NEXP];
        int top = 0;
#pragma unroll
        for (int e = 0; e < NEXP; e++) {
            g[e] = p[e] * invs;
            gates[(size_t)n * NEXP + e] = g[e];
            if (g[e] > g[top]) top = e;
        }
        float w[NEXP], sm = 0.0f;
        int c = 0;
#pragma unroll
        for (int e = 0; e < NEXP; e++) {
            const bool mk = (g[e] >= 0.3f);
            const float ms = mk ? g[e] : 0.0f;
            sm += ms; c += mk ? 1 : 0;
            w[e] = ms;
        }
        if (c == 0) {
#pragma unroll
            for (int e = 0; e < NEXP; e++) w[e] = 0.0f;
            w[top] = 1.0f;
        } else {
            const float inv = 1.0f / (sm + 1e-6f);
#pragma unroll
            for (int e = 0; e < NEXP; e++) w[e] *= inv;
        }
#pragma unroll
        for (int e = 0; e < NEXP; e++) {
            wts[(size_t)n * NEXP + e] = w[e];
            if (w[e] > 0.0f) atomicAdd(&cnt[e], 1);
        }
    }
}

// ---------------- offsets: exclusive prefix over cnt; zero cnt2 --------------
__global__ void offsets_kernel(const int* __restrict__ cnt, int* __restrict__ off,
                               int* __restrict__ cnt2)
{
    if (threadIdx.x == 0) {
        int a = 0;
        for (int e = 0; e < NEXP; e++) { off[e] = a; a += cnt[e]; cnt2[e] = 0; }
    }
}

// ---------------- build per-expert gathered row lists ------------------------
__global__ __launch_bounds__(256)
void build_list_kernel(const float* __restrict__ wts, const int* __restrict__ off,
                       int* __restrict__ cnt2, int* __restrict__ gidx,
                       float* __restrict__ wpk)
{
    const int n = blockIdx.x * 256 + threadIdx.x;
    if (n >= N_TOK) return;
#pragma unroll
    for (int e = 0; e < NEXP; e++) {
        const float w = wts[(size_t)n * NEXP + e];
        if (w > 0.0f) {
            const int slot = atomicAdd(&cnt2[e], 1);
            const int g = off[e] + slot;
            gidx[g] = n;
            wpk[g] = w;
        }
    }
}

// ---------------- gather rows of expert_inputs -> packed bf16 ----------------
__global__ __launch_bounds__(256)
void gather_cvt_kernel(const float* __restrict__ ei, const int* __restrict__ cnt,
                       const int* __restrict__ off, const int* __restrict__ gidx,
                       unsigned short* __restrict__ xg)
{
    const int e = blockIdx.y;
    const int ne = cnt[e];
    const int i0 = blockIdx.x * 8;
    if (i0 >= ne) return;
    const int grp = threadIdx.x >> 5;   // 8 groups of 32 lanes, one row each
    const int l32 = threadIdx.x & 31;
    const int i = i0 + grp;
    if (i >= ne) return;
    const int o = off[e];
    const float* src = ei + ((size_t)e * N_TOK + gidx[o + i]) * DIM_;
    unsigned short* dst = xg + (size_t)(o + i) * DIM_;
#pragma unroll
    for (int j = 0; j < 8; j++) {
        const int c = (l32 + j * 32) * 4;
        const float4 v = *(const float4*)(src + c);
        ushort4 u;
        u.x = f32_to_bf16(v.x); u.y = f32_to_bf16(v.y);
        u.z = f32_to_bf16(v.z); u.w = f32_to_bf16(v.w);
        *(ushort4*)(dst + c) = u;
    }
}

// ---------------- fp32 [E][R][C] -> bf16 [E][C][R], coalesced ushort2 stores -
__global__ __launch_bounds__(256)
void transpose_cvt2(const float* __restrict__ in, unsigned short* __restrict__ out,
                    int R, int C)
{
    __shared__ float tile[64][33];
    const int e  = blockIdx.z;
    const int c0 = blockIdx.x * 32;
    const int r0 = blockIdx.y * 64;
    const int tx = threadIdx.x & 31;
    const int ty = threadIdx.x >> 5;    // 0..7
    const float* src = in + (size_t)e * R * C;
#pragma unroll
    for (int i = 0; i < 8; i++)
        tile[ty + i * 8][tx] = src[(size_t)(r0 + ty + i * 8) * C + (c0 + tx)];
    __syncthreads();
    unsigned short* dst = out + (size_t)e * R * C;
#pragma unroll
    for (int i = 0; i < 4; i++) {
        const int c = ty + i * 8;
        ushort2 p;
        p.x = f32_to_bf16(tile[2 * tx][c]);
        p.y = f32_to_bf16(tile[2 * tx + 1][c]);
        *(ushort2*)&dst[(size_t)(c0 + c) * R + r0 + 2 * tx] = p;
    }
}

// ---------------- GEMM1: h = gelu(Xg @ W1 + b1), batched over experts --------
// grid: (HHALF/128, 32, E); early-exit on gathered row count.
__global__ __launch_bounds__(256)
void gemm1_k(const unsigned short* __restrict__ xg, const unsigned short* __restrict__ w1t,
             const float* __restrict__ b1, unsigned short* __restrict__ hg,
             const int* __restrict__ cnt, const int* __restrict__ off, int h0)
{
    const int e = blockIdx.z;
    const int ne = cnt[e];
    const int rowBase = blockIdx.y * 128;
    if (rowBase >= ne) return;
    const int o = off[e];
    const int colBase = blockIdx.x * 128;

    __shared__ __align__(16) unsigned short sA[128 * 32];
    __shared__ __align__(16) unsigned short sB[128 * 32];
    const int tid  = threadIdx.x;
    const int lane = tid & 63;
    const int wave = tid >> 6;
    const int wr = wave >> 1, wc = wave & 1;

    f32x4 acc[4][4];
#pragma unroll
    for (int i = 0; i < 4; i++)
#pragma unroll
        for (int j = 0; j < 4; j++)
#pragma unroll
            for (int r = 0; r < 4; r++) acc[i][j][r] = 0.0f;

    const int sr = tid >> 2;
    const int sc = (tid & 3) << 3;
    const int row0 = min(rowBase + sr, ne - 1);
    const int row1 = min(rowBase + 64 + sr, ne - 1);
    const unsigned short* ga0 = xg + (size_t)(o + row0) * DIM_ + sc;
    const unsigned short* ga1 = xg + (size_t)(o + row1) * DIM_ + sc;
    const unsigned short* gb0 = w1t + ((size_t)e * HID_ + h0 + colBase + sr) * DIM_ + sc;
    const unsigned short* gb1 = gb0 + (size_t)64 * DIM_;
    unsigned short* la0 = sA + tid * 8;
    unsigned short* la1 = sA + 2048 + tid * 8;
    unsigned short* lb0 = sB + tid * 8;
    unsigned short* lb1 = sB + 2048 + tid * 8;

    const int aoff = (wr * 64 + (lane & 15)) * 32 + ((lane >> 4) << 3);
    const int boff = (wc * 64 + (lane & 15)) * 32 + ((lane >> 4) << 3);

    for (int k0 = 0; k0 < DIM_; k0 += 32) {
        gl_lds16(ga0 + k0, la0);
        gl_lds16(ga1 + k0, la1);
        gl_lds16(gb0 + k0, lb0);
        gl_lds16(gb1 + k0, lb1);
        __syncthreads();
        short8 av[4], bv[4];
#pragma unroll
        for (int i = 0; i < 4; i++) av[i] = *(const short8*)(sA + aoff + i * 16 * 32);
#pragma unroll
        for (int j = 0; j < 4; j++) bv[j] = *(const short8*)(sB + boff + j * 16 * 32);
#pragma unroll
        for (int i = 0; i < 4; i++)
#pragma unroll
            for (int j = 0; j < 4; j++)
                acc[i][j] = __builtin_amdgcn_mfma_f32_16x16x32_bf16(av[i], bv[j], acc[i][j], 0, 0, 0);
        __syncthreads();
    }

    const int crow = rowBase + wr * 64 + ((lane >> 4) << 2);
    const int ccol = colBase + wc * 64 + (lane & 15);
#pragma unroll
    for (int i = 0; i < 4; i++) {
#pragma unroll
        for (int j = 0; j < 4; j++) {
            const int col = ccol + j * 16;
            const float b = b1[(size_t)e * HID_ + h0 + col];
#pragma unroll
            for (int r = 0; r < 4; r++) {
                const int row = crow + i * 16 + r;
                if (row < ne) {
                    const float v = acc[i][j][r] + b;
                    hg[(size_t)(o + row) * HHALF + col] = f32_to_bf16(gelu_exact(v));
                }
            }
        }
    }
}

// ---------------- GEMM2: fused[gidx[r]] += w * (Hg @ W2 + b2), atomic scatter
// grid: (DIM/128, 32, E); K = HHALF chunk of HID (bias added on h0==0 chunk).
__global__ __launch_bounds__(256)
void gemm2_k(const unsigned short* __restrict__ hg, const unsigned short* __restrict__ w2t,
             const float* __restrict__ b2, float* __restrict__ fused,
             const int* __restrict__ cnt, const int* __restrict__ off,
             const int* __restrict__ gidx, const float* __restrict__ wpk, int h0)
{
    const int e = blockIdx.z;
    const int ne = cnt[e];
    const int rowBase = blockIdx.y * 128;
    if (rowBase >= ne) return;
    const int o = off[e];
    const int colBase = blockIdx.x * 128;

    __shared__ __align__(16) unsigned short sA[128 * 32];
    __shared__ __align__(16) unsigned short sB[128 * 32];
    const int tid  = threadIdx.x;
    const int lane = tid & 63;
    const int wave = tid >> 6;
    const int wr = wave >> 1, wc = wave & 1;

    f32x4 acc[4][4];
#pragma unroll
    for (int i = 0; i < 4; i++)
#pragma unroll
        for (int j = 0; j < 4; j++)
#pragma unroll
            for (int r = 0; r < 4; r++) acc[i][j][r] = 0.0f;

    const int sr = tid >> 2;
    const int sc = (tid & 3) << 3;
    const int row0 = min(rowBase + sr, ne - 1);
    const int row1 = min(rowBase + 64 + sr, ne - 1);
    const unsigned short* ga0 = hg + (size_t)(o + row0) * HHALF + sc;
    const unsigned short* ga1 = hg + (size_t)(o + row1) * HHALF + sc;
    const unsigned short* gb0 = w2t + ((size_t)e * DIM_ + colBase + sr) * HID_ + h0 + sc;
    const unsigned short* gb1 = gb0 + (size_t)64 * HID_;
    unsigned short* la0 = sA + tid * 8;
    unsigned short* la1 = sA + 2048 + tid * 8;
    unsigned short* lb0 = sB + tid * 8;
    unsigned short* lb1 = sB + 2048 + tid * 8;

    const int aoff = (wr * 64 + (lane & 15)) * 32 + ((lane >> 4) << 3);
    const int boff = (wc * 64 + (lane & 15)) * 32 + ((lane >> 4) << 3);

    for (int k0 = 0; k0 < HHALF; k0 += 32) {
        gl_lds16(ga0 + k0, la0);
        gl_lds16(ga1 + k0, la1);
        gl_lds16(gb0 + k0, lb0);
        gl_lds16(gb1 + k0, lb1);
        __syncthreads();
        short8 av[4], bv[4];
#pragma unroll
        for (int i = 0; i < 4; i++) av[i] = *(const short8*)(sA + aoff + i * 16 * 32);
#pragma unroll
        for (int j = 0; j < 4; j++) bv[j] = *(const short8*)(sB + boff + j * 16 * 32);
#pragma unroll
        for (int i = 0; i < 4; i++)
#pragma unroll
            for (int j = 0; j < 4; j++)
                acc[i][j] = __builtin_amdgcn_mfma_f32_16x16x32_bf16(av[i], bv[j], acc[i][j], 0, 0, 0);
        __syncthreads();
    }

    const int crow = rowBase + wr * 64 + ((lane >> 4) << 2);
    const int ccol = colBase + wc * 64 + (lane & 15);
#pragma unroll
    for (int i = 0; i < 4; i++) {
#pragma unroll
        for (int j = 0; j < 4; j++) {
            const int col = ccol + j * 16;
            const float b = (h0 == 0) ? b2[(size_t)e * DIM_ + col] : 0.0f;
#pragma unroll
            for (int r = 0; r < 4; r++) {
                const int row = crow + i * 16 + r;
                if (row < ne) {
                    const float w = wpk[o + row];
                    const int orow = gidx[o + row];
                    atomicAdd(&fused[(size_t)orow * DIM_ + col], w * (acc[i][j][r] + b));
                }
            }
        }
    }
}

extern "C" void kernel_launch(void* const* d_in, const int* in_sizes, int n_in,
                              void* d_out, int out_size, void* d_ws, size_t ws_size,
                              hipStream_t stream)
{
    const float* x  = (const float*)d_in[0];
    const float* ei = (const float*)d_in[1];
    const float* wg = (const float*)d_in[2];
    const float* bg = (const float*)d_in[3];
    const float* w1 = (const float*)d_in[4];
    const float* b1 = (const float*)d_in[5];
    const float* w2 = (const float*)d_in[6];
    const float* b2 = (const float*)d_in[7];

    float* fused = (float*)d_out;                    // [N, DIM]
    float* gates = fused + (size_t)N_TOK * DIM_;     // [N, E]

    // workspace (~210 MB < 235 MB proven in round 1)
    unsigned short* xg  = (unsigned short*)d_ws;                   // [CAP][DIM] bf16   25.2 MB
    unsigned short* hg  = xg  + (size_t)CAP * DIM_;                // [CAP][HHALF] bf16 50.3 MB
    unsigned short* w1t = hg  + (size_t)CAP * HHALF;               // [E][HID][DIM]     67.1 MB
    unsigned short* w2t = w1t + (size_t)NEXP * HID_ * DIM_;        // [E][DIM][HID]     67.1 MB
    float* wts = (float*)(w2t + (size_t)NEXP * DIM_ * HID_);       // [N][E]
    float* wpk = wts + (size_t)N_TOK * NEXP;                       // [CAP]
    int* gidx  = (int*)(wpk + CAP);                                // [CAP]
    int* cnt   = gidx + CAP;                                       // [E]
    int* off   = cnt + NEXP;                                       // [E]
    int* cnt2  = off + NEXP;                                       // [E]

    // 1) zero fused + counters; gate (scores, weights, per-expert counts)
    zero_init_kernel<<<N_TOK + 1, 256, 0, stream>>>(fused, cnt);
    gate_kernel<<<N_TOK, 256, 0, stream>>>(x, wg, bg, gates, wts, cnt);
    offsets_kernel<<<1, 64, 0, stream>>>(cnt, off, cnt2);
    build_list_kernel<<<N_TOK / 256, 256, 0, stream>>>(wts, off, cnt2, gidx, wpk);

    // 2) operand prep: gather+convert expert inputs; transpose+convert weights
    gather_cvt_kernel<<<dim3(N_TOK / 8, NEXP), 256, 0, stream>>>(ei, cnt, off, gidx, xg);
    transpose_cvt2<<<dim3(HID_ / 32, DIM_ / 64, NEXP), 256, 0, stream>>>(w1, w1t, DIM_, HID_);
    transpose_cvt2<<<dim3(DIM_ / 32, HID_ / 64, NEXP), 256, 0, stream>>>(w2, w2t, HID_, DIM_);

    // 3) FFN on gathered rows only, HID in two halves (h buffer reuse)
    for (int h0 = 0; h0 < HID_; h0 += HHALF) {
        gemm1_k<<<dim3(HHALF / 128, N_TOK / 128, NEXP), 256, 0, stream>>>(
            xg, w1t, b1, hg, cnt, off, h0);
        gemm2_k<<<dim3(DIM_ / 128, N_TOK / 128, NEXP), 256, 0, stream>>>(
            hg, w2t, b2, fused, cnt, off, gidx, wpk, h0);
    }
}

// Round 3
// 670.481 us; speedup vs baseline: 2.8221x; 1.0680x over previous
//
#include <hip/hip_runtime.h>
#include <hip/hip_bf16.h>
#include <cstdint>

#define N_TOK 4096
#define DIM_  1024
#define HID_  4096
#define NEXP  8
#define HHALF 2048           // HID processed in two halves (h buffer reuse)
#define CAP   (3 * N_TOK)    // Sum n_e <= 3N (at most 3 gates can be >= 0.3)

typedef __attribute__((ext_vector_type(8))) short short8;
typedef __attribute__((ext_vector_type(4))) float f32x4;

__device__ __forceinline__ unsigned short f32_to_bf16(float f) {
    union { float f; uint32_t u; } v;
    v.f = f;
    uint32_t r = (v.u + 0x7fffu + ((v.u >> 16) & 1u)) >> 16;
    return (unsigned short)r;
}

__device__ __forceinline__ float gelu_exact(float x) {
    return 0.5f * x * (1.0f + erff(x * 0.70710678118654752440f));
}

__device__ __forceinline__ void gl_lds16(const unsigned short* g, unsigned short* l) {
    __builtin_amdgcn_global_load_lds(
        (const __attribute__((address_space(1))) void*)g,
        (__attribute__((address_space(3))) void*)l, 16, 0, 0);
}

// ---------------- zero-init fused output + per-expert counters ---------------
__global__ __launch_bounds__(256)
void zero_init_kernel(float* __restrict__ fused, int* __restrict__ cnt)
{
    const int b = blockIdx.x;
    if (b < N_TOK) {
        float4* p = (float4*)(fused + (size_t)b * DIM_);
        p[threadIdx.x] = make_float4(0.f, 0.f, 0.f, 0.f);
    } else if (threadIdx.x < NEXP) {
        cnt[threadIdx.x] = 0;
    }
}

// ---------------- Gate: one wave per row; softmax -> mask/renorm/fallback ----
__global__ __launch_bounds__(256)
void gate_kernel(const float* __restrict__ x, const float* __restrict__ wg,
                 const float* __restrict__ bg, float* __restrict__ gates,
                 float* __restrict__ wts, int* __restrict__ cnt)
{
    const int wave = threadIdx.x >> 6;
    const int lane = threadIdx.x & 63;
    const int n = blockIdx.x * 4 + wave;
    float acc[NEXP];
#pragma unroll
    for (int e = 0; e < NEXP; e++) acc[e] = 0.0f;
    const float4* xr = (const float4*)(x + (size_t)n * DIM_);
#pragma unroll
    for (int j = 0; j < 4; j++) {
        const int k4 = lane + j * 64;
        const float4 v = xr[k4];
        const float* wr = wg + (size_t)k4 * 4 * NEXP;
#pragma unroll
        for (int e = 0; e < NEXP; e++)
            acc[e] += v.x * wr[e] + v.y * wr[NEXP + e] +
                      v.z * wr[2 * NEXP + e] + v.w * wr[3 * NEXP + e];
    }
#pragma unroll
    for (int e = 0; e < NEXP; e++) {
#pragma unroll
        for (int off = 32; off > 0; off >>= 1)
            acc[e] += __shfl_xor(acc[e], off, 64);
    }
    if (lane == 0) {
        float z[NEXP];
#pragma unroll
        for (int e = 0; e < NEXP; e++) z[e] = acc[e] + bg[e];
        float m = z[0];
#pragma unroll
        for (int e = 1; e < NEXP; e++) m = fmaxf(m, z[e]);
        float p[NEXP], s = 0.0f;
#pragma unroll
        for (int e = 0; e < NEXP; e++) { p[e] = __expf(z[e] - m); s += p[e]; }
        const float invs = 1.0f / s;
        float g[NEXP];
        int top = 0;
#pragma unroll
        for (int e = 0; e < NEXP; e++) {
            g[e] = p[e] * invs;
            gates[(size_t)n * NEXP + e] = g[e];
            if (g[e] > g[top]) top = e;
        }
        float w[NEXP], sm = 0.0f;
        int c = 0;
#pragma unroll
        for (int e = 0; e < NEXP; e++) {
            const bool mk = (g[e] >= 0.3f);
            const float ms = mk ? g[e] : 0.0f;
            sm += ms; c += mk ? 1 : 0;
            w[e] = ms;
        }
        if (c == 0) {
#pragma unroll
            for (int e = 0; e < NEXP; e++) w[e] = 0.0f;
            w[top] = 1.0f;
        } else {
            const float inv = 1.0f / (sm + 1e-6f);
#pragma unroll
            for (int e = 0; e < NEXP; e++) w[e] *= inv;
        }
#pragma unroll
        for (int e = 0; e < NEXP; e++) {
            wts[(size_t)n * NEXP + e] = w[e];
            if (w[e] > 0.0f) atomicAdd(&cnt[e], 1);
        }
    }
}

// ---------------- offsets: exclusive prefix over cnt; zero cnt2 --------------
__global__ void offsets_kernel(const int* __restrict__ cnt, int* __restrict__ off,
                               int* __restrict__ cnt2)
{
    if (threadIdx.x == 0) {
        int a = 0;
        for (int e = 0; e < NEXP; e++) { off[e] = a; a += cnt[e]; cnt2[e] = 0; }
    }
}

// ---------------- build per-expert gathered row lists ------------------------
__global__ __launch_bounds__(256)
void build_list_kernel(const float* __restrict__ wts, const int* __restrict__ off,
                       int* __restrict__ cnt2, int* __restrict__ gidx,
                       float* __restrict__ wpk)
{
    const int n = blockIdx.x * 256 + threadIdx.x;
    if (n >= N_TOK) return;
#pragma unroll
    for (int e = 0; e < NEXP; e++) {
        const float w = wts[(size_t)n * NEXP + e];
        if (w > 0.0f) {
            const int slot = atomicAdd(&cnt2[e], 1);
            const int g = off[e] + slot;
            gidx[g] = n;
            wpk[g] = w;
        }
    }
}

// ---------------- gather rows of expert_inputs -> packed bf16 ----------------
__global__ __launch_bounds__(256)
void gather_cvt_kernel(const float* __restrict__ ei, const int* __restrict__ cnt,
                       const int* __restrict__ off, const int* __restrict__ gidx,
                       unsigned short* __restrict__ xg)
{
    const int e = blockIdx.y;
    const int ne = cnt[e];
    const int i0 = blockIdx.x * 8;
    if (i0 >= ne) return;
    const int grp = threadIdx.x >> 5;
    const int l32 = threadIdx.x & 31;
    const int i = i0 + grp;
    if (i >= ne) return;
    const int o = off[e];
    const float* src = ei + ((size_t)e * N_TOK + gidx[o + i]) * DIM_;
    unsigned short* dst = xg + (size_t)(o + i) * DIM_;
#pragma unroll
    for (int j = 0; j < 8; j++) {
        const int c = (l32 + j * 32) * 4;
        const float4 v = *(const float4*)(src + c);
        ushort4 u;
        u.x = f32_to_bf16(v.x); u.y = f32_to_bf16(v.y);
        u.z = f32_to_bf16(v.z); u.w = f32_to_bf16(v.w);
        *(ushort4*)(dst + c) = u;
    }
}

// ------- both weight transposes in one dispatch: fp32 [R][C] -> bf16 [C][R] --
__global__ __launch_bounds__(256)
void transpose_cvt3(const float* __restrict__ w1, const float* __restrict__ w2,
                    unsigned short* __restrict__ w1t, unsigned short* __restrict__ w2t)
{
    __shared__ float tile[64][33];
    const int z = blockIdx.y;       // 0..7 -> w1 expert z; 8..15 -> w2 expert z-8
    const float* src;
    unsigned short* dst;
    int cb, rb;
    if (z < NEXP) {
        src = w1 + (size_t)z * DIM_ * HID_;
        dst = w1t + (size_t)z * DIM_ * HID_;
        cb = blockIdx.x & 127; rb = blockIdx.x >> 7;   // C=HID (128 cblk), R=DIM (16 rblk)
    } else {
        src = w2 + (size_t)(z - NEXP) * HID_ * DIM_;
        dst = w2t + (size_t)(z - NEXP) * HID_ * DIM_;
        cb = blockIdx.x & 31; rb = blockIdx.x >> 5;    // C=DIM (32 cblk), R=HID (64 rblk)
    }
    const int C = (z < NEXP) ? HID_ : DIM_;
    const int R = (z < NEXP) ? DIM_ : HID_;
    const int c0 = cb * 32;
    const int r0 = rb * 64;
    const int tx = threadIdx.x & 31;
    const int ty = threadIdx.x >> 5;
#pragma unroll
    for (int i = 0; i < 8; i++)
        tile[ty + i * 8][tx] = src[(size_t)(r0 + ty + i * 8) * C + (c0 + tx)];
    __syncthreads();
#pragma unroll
    for (int i = 0; i < 4; i++) {
        const int c = ty + i * 8;
        ushort2 p;
        p.x = f32_to_bf16(tile[2 * tx][c]);
        p.y = f32_to_bf16(tile[2 * tx + 1][c]);
        *(ushort2*)&dst[(size_t)(c0 + c) * R + r0 + 2 * tx] = p;
    }
}

// ---------------- GEMM1: h = gelu(Xg @ W1 + b1); 64x128 tile, batched --------
// grid: (HHALF/128, N_TOK/64, E); early-exit on gathered row count.
__global__ __launch_bounds__(256)
void gemm1_k(const unsigned short* __restrict__ xg, const unsigned short* __restrict__ w1t,
             const float* __restrict__ b1, unsigned short* __restrict__ hg,
             const int* __restrict__ cnt, const int* __restrict__ off, int h0)
{
    const int e = blockIdx.z;
    const int ne = cnt[e];
    const int rowBase = blockIdx.y * 64;
    if (rowBase >= ne) return;
    const int o = off[e];
    const int colBase = blockIdx.x * 128;

    __shared__ __align__(16) unsigned short sA[64 * 32];
    __shared__ __align__(16) unsigned short sB[128 * 32];
    const int tid  = threadIdx.x;
    const int lane = tid & 63;
    const int wave = tid >> 6;
    const int wr = wave >> 1, wc = wave & 1;   // 2x2 waves: 32 rows x 64 cols each

    f32x4 acc[2][4];
#pragma unroll
    for (int i = 0; i < 2; i++)
#pragma unroll
        for (int j = 0; j < 4; j++)
#pragma unroll
            for (int r = 0; r < 4; r++) acc[i][j][r] = 0.0f;

    const int sr = tid >> 2;            // 0..63
    const int sc = (tid & 3) << 3;
    const int rowA = min(rowBase + sr, ne - 1);
    const unsigned short* ga0 = xg + (size_t)(o + rowA) * DIM_ + sc;
    const unsigned short* gb0 = w1t + ((size_t)e * HID_ + h0 + colBase + sr) * DIM_ + sc;
    const unsigned short* gb1 = gb0 + (size_t)64 * DIM_;
    unsigned short* la0 = sA + tid * 8;
    unsigned short* lb0 = sB + tid * 8;
    unsigned short* lb1 = sB + 2048 + tid * 8;

    const int aoff = (wr * 32 + (lane & 15)) * 32 + ((lane >> 4) << 3);
    const int boff = (wc * 64 + (lane & 15)) * 32 + ((lane >> 4) << 3);

    for (int k0 = 0; k0 < DIM_; k0 += 32) {
        gl_lds16(ga0 + k0, la0);
        gl_lds16(gb0 + k0, lb0);
        gl_lds16(gb1 + k0, lb1);
        __syncthreads();
        short8 av[2], bv[4];
#pragma unroll
        for (int i = 0; i < 2; i++) av[i] = *(const short8*)(sA + aoff + i * 16 * 32);
#pragma unroll
        for (int j = 0; j < 4; j++) bv[j] = *(const short8*)(sB + boff + j * 16 * 32);
#pragma unroll
        for (int i = 0; i < 2; i++)
#pragma unroll
            for (int j = 0; j < 4; j++)
                acc[i][j] = __builtin_amdgcn_mfma_f32_16x16x32_bf16(av[i], bv[j], acc[i][j], 0, 0, 0);
        __syncthreads();
    }

    const int crow = rowBase + wr * 32 + ((lane >> 4) << 2);
    const int ccol = colBase + wc * 64 + (lane & 15);
#pragma unroll
    for (int i = 0; i < 2; i++) {
#pragma unroll
        for (int j = 0; j < 4; j++) {
            const int col = ccol + j * 16;
            const float b = b1[(size_t)e * HID_ + h0 + col];
#pragma unroll
            for (int r = 0; r < 4; r++) {
                const int row = crow + i * 16 + r;
                if (row < ne) {
                    const float v = acc[i][j][r] + b;
                    hg[(size_t)(o + row) * HHALF + col] = f32_to_bf16(gelu_exact(v));
                }
            }
        }
    }
}

// -------- GEMM2: fused[gidx[r]] += w * (Hg @ W2 + b2); 64x128 tile, split-K=2
// grid: (16 = 8 colBlk x 2 kChunk, N_TOK/64, E).
__global__ __launch_bounds__(256)
void gemm2_k(const unsigned short* __restrict__ hg, const unsigned short* __restrict__ w2t,
             const float* __restrict__ b2, float* __restrict__ fused,
             const int* __restrict__ cnt, const int* __restrict__ off,
             const int* __restrict__ gidx, const float* __restrict__ wpk, int h0)
{
    const int e = blockIdx.z;
    const int ne = cnt[e];
    const int rowBase = blockIdx.y * 64;
    if (rowBase >= ne) return;
    const int o = off[e];
    const int colBase = (blockIdx.x & 7) * 128;
    const int kc = blockIdx.x >> 3;            // 0,1 : K chunk of 1024 within HHALF
    const int kbeg = kc * (HHALF / 2);

    __shared__ __align__(16) unsigned short sA[64 * 32];
    __shared__ __align__(16) unsigned short sB[128 * 32];
    const int tid  = threadIdx.x;
    const int lane = tid & 63;
    const int wave = tid >> 6;
    const int wr = wave >> 1, wc = wave & 1;

    f32x4 acc[2][4];
#pragma unroll
    for (int i = 0; i < 2; i++)
#pragma unroll
        for (int j = 0; j < 4; j++)
#pragma unroll
            for (int r = 0; r < 4; r++) acc[i][j][r] = 0.0f;

    const int sr = tid >> 2;
    const int sc = (tid & 3) << 3;
    const int rowA = min(rowBase + sr, ne - 1);
    const unsigned short* ga0 = hg + (size_t)(o + rowA) * HHALF + kbeg + sc;
    const unsigned short* gb0 = w2t + ((size_t)e * DIM_ + colBase + sr) * HID_ + h0 + kbeg + sc;
    const unsigned short* gb1 = gb0 + (size_t)64 * HID_;
    unsigned short* la0 = sA + tid * 8;
    unsigned short* lb0 = sB + tid * 8;
    unsigned short* lb1 = sB + 2048 + tid * 8;

    const int aoff = (wr * 32 + (lane & 15)) * 32 + ((lane >> 4) << 3);
    const int boff = (wc * 64 + (lane & 15)) * 32 + ((lane >> 4) << 3);

    for (int k0 = 0; k0 < HHALF / 2; k0 += 32) {
        gl_lds16(ga0 + k0, la0);
        gl_lds16(gb0 + k0, lb0);
        gl_lds16(gb1 + k0, lb1);
        __syncthreads();
        short8 av[2], bv[4];
#pragma unroll
        for (int i = 0; i < 2; i++) av[i] = *(const short8*)(sA + aoff + i * 16 * 32);
#pragma unroll
        for (int j = 0; j < 4; j++) bv[j] = *(const short8*)(sB + boff + j * 16 * 32);
#pragma unroll
        for (int i = 0; i < 2; i++)
#pragma unroll
            for (int j = 0; j < 4; j++)
                acc[i][j] = __builtin_amdgcn_mfma_f32_16x16x32_bf16(av[i], bv[j], acc[i][j], 0, 0, 0);
        __syncthreads();
    }

    const int crow = rowBase + wr * 32 + ((lane >> 4) << 2);
    const int ccol = colBase + wc * 64 + (lane & 15);
    const int addBias = (h0 == 0 && kc == 0);
#pragma unroll
    for (int i = 0; i < 2; i++) {
#pragma unroll
        for (int j = 0; j < 4; j++) {
            const int col = ccol + j * 16;
            const float b = addBias ? b2[(size_t)e * DIM_ + col] : 0.0f;
#pragma unroll
            for (int r = 0; r < 4; r++) {
                const int row = crow + i * 16 + r;
                if (row < ne) {
                    const float w = wpk[o + row];
                    const int orow = gidx[o + row];
                    atomicAdd(&fused[(size_t)orow * DIM_ + col], w * (acc[i][j][r] + b));
                }
            }
        }
    }
}

extern "C" void kernel_launch(void* const* d_in, const int* in_sizes, int n_in,
                              void* d_out, int out_size, void* d_ws, size_t ws_size,
                              hipStream_t stream)
{
    const float* x  = (const float*)d_in[0];
    const float* ei = (const float*)d_in[1];
    const float* wg = (const float*)d_in[2];
    const float* bg = (const float*)d_in[3];
    const float* w1 = (const float*)d_in[4];
    const float* b1 = (const float*)d_in[5];
    const float* w2 = (const float*)d_in[6];
    const float* b2 = (const float*)d_in[7];

    float* fused = (float*)d_out;                    // [N, DIM]
    float* gates = fused + (size_t)N_TOK * DIM_;     // [N, E]

    // workspace (~210 MB; 235 MB proven safe in round 1)
    unsigned short* xg  = (unsigned short*)d_ws;                   // [CAP][DIM] bf16
    unsigned short* hg  = xg  + (size_t)CAP * DIM_;                // [CAP][HHALF] bf16
    unsigned short* w1t = hg  + (size_t)CAP * HHALF;               // [E][HID][DIM]
    unsigned short* w2t = w1t + (size_t)NEXP * HID_ * DIM_;        // [E][DIM][HID]
    float* wts = (float*)(w2t + (size_t)NEXP * DIM_ * HID_);       // [N][E]
    float* wpk = wts + (size_t)N_TOK * NEXP;                       // [CAP]
    int* gidx  = (int*)(wpk + CAP);                                // [CAP]
    int* cnt   = gidx + CAP;                                       // [E]
    int* off   = cnt + NEXP;                                       // [E]
    int* cnt2  = off + NEXP;                                       // [E]

    zero_init_kernel<<<N_TOK + 1, 256, 0, stream>>>(fused, cnt);
    gate_kernel<<<N_TOK / 4, 256, 0, stream>>>(x, wg, bg, gates, wts, cnt);
    offsets_kernel<<<1, 64, 0, stream>>>(cnt, off, cnt2);
    build_list_kernel<<<N_TOK / 256, 256, 0, stream>>>(wts, off, cnt2, gidx, wpk);

    gather_cvt_kernel<<<dim3(N_TOK / 8, NEXP), 256, 0, stream>>>(ei, cnt, off, gidx, xg);
    transpose_cvt3<<<dim3(2048, 16), 256, 0, stream>>>(w1, w2, w1t, w2t);

    for (int h0 = 0; h0 < HID_; h0 += HHALF) {
        gemm1_k<<<dim3(HHALF / 128, N_TOK / 64, NEXP), 256, 0, stream>>>(
            xg, w1t, b1, hg, cnt, off, h0);
        gemm2_k<<<dim3(16, N_TOK / 64, NEXP), 256, 0, stream>>>(
            hg, w2t, b2, fused, cnt, off, gidx, wpk, h0);
    }
}